// Round 3
// baseline (172.087 us; speedup 1.0000x reference)
//
#include <hip/hip_runtime.h>
#include <hip/hip_cooperative_groups.h>
#include <math.h>

namespace cg = cooperative_groups;

#define N_AGENTS 1024
#define HIDDEN   128
#define GRIDSZ   32
#define NCELLS   1024
#define KDIM     2048
#define NBLK     256
#define NTHR     512
#define NSPLIT   4     // k-splits in MFMA phase (KCHUNK = 512)

typedef __attribute__((ext_vector_type(8))) short short8;   // 8 bf16 = 4 VGPRs
typedef __attribute__((ext_vector_type(4))) float floatx4;  // MFMA accumulator

static __device__ __forceinline__ ushort f2bf(float x) {   // RNE fp32->bf16
    union { float f; unsigned u; } v; v.f = x;
    return (ushort)((v.u + 0x7fffu + ((v.u >> 16) & 1u)) >> 16);
}

__global__ __launch_bounds__(NTHR, 2) void k_fused(
        const float* __restrict__ hidden, const float* __restrict__ obs2,
        const float* __restrict__ W, const float* __restrict__ bias,
        float* __restrict__ out,
        float* __restrict__ Sh, ushort* __restrict__ Wb,
        ushort* __restrict__ Gb, float* __restrict__ part) {
    cg::grid_group grid = cg::this_grid();
    __shared__ float2 spos[N_AGENTS];   // 8 KB
    __shared__ float4 ssh[N_AGENTS];    // 16 KB
    __shared__ int win[4][NCELLS];      // 16 KB

    const int tid = threadIdx.x;
    const int gt = blockIdx.x * NTHR + tid;   // 0..131071

    // ---- P1a: Wb = bf16(W); 262144 elems, 2 per thread (float2 load, packed store)
    {
        float2 w2 = ((const float2*)W)[gt];
        ((unsigned*)Wb)[gt] = (unsigned)f2bf(w2.x) | ((unsigned)f2bf(w2.y) << 16);
    }
    // ---- P1b: Sh[j][c] = sum over d with ((d>>3)&3)==c of hidden[j][d]
    if (gt < N_AGENTS * 4) {
        int j = gt >> 2, c = gt & 3;
        const float* h = hidden + j * HIDDEN + c * 8;
        float s = 0.f;
#pragma unroll
        for (int u = 0; u < 4; ++u) {
            float4 a = *(const float4*)(h + u * 32);
            float4 b = *(const float4*)(h + u * 32 + 4);
            s += a.x + a.y + a.z + a.w + b.x + b.y + b.z + b.w;
        }
        Sh[gt] = s;
    }
    grid.sync();

    // ---- P2: 4 agents per block; one j-scan fills 4 winner grids (set == max-j)
    {
        const float2* o2 = (const float2*)obs2;
        const float4* Sh4 = (const float4*)Sh;
        for (int j = tid; j < N_AGENTS; j += NTHR) {   // 2 iters
            spos[j] = o2[j];
            ssh[j] = Sh4[j];
        }
#pragma unroll
        for (int a = 0; a < 4; ++a)
            for (int c = tid; c < NCELLS; c += NTHR)
                win[a][c] = -1;
        __syncthreads();
        const int ibase = blockIdx.x * 4;
        float2 pi[4];
#pragma unroll
        for (int a = 0; a < 4; ++a) pi[a] = spos[ibase + a];
        for (int j = tid; j < N_AGENTS; j += NTHR) {   // 2 iters
            float2 pj = spos[j];
            if (isnan(pj.x)) continue;
#pragma unroll
            for (int a = 0; a < 4; ++a) {
                if (j == ibase + a) continue;
                // exact reference fp32 math: /0.125 == *8 (exact), then +16
                float rx = (pj.x - pi[a].x) * 8.0f + 16.0f;   // NaN pi -> cmps false
                float ry = (pj.y - pi[a].y) * 8.0f + 16.0f;
                if (rx >= 0.f && rx < 32.f && ry >= 0.f && ry < 32.f)
                    atomicMax(&win[a][(int)rx * GRIDSZ + (int)ry], j);
            }
        }
        __syncthreads();
        // pooling: thread == cell-pair p; fp32 sum, single bf16 round, 8B store
        int p = tid;   // 0..511
#pragma unroll
        for (int a = 0; a < 4; ++a) {
            int w0 = win[a][2 * p], w1 = win[a][2 * p + 1];
            float4 v = {0.f, 0.f, 0.f, 0.f};
            if (w0 >= 0) { float4 s = ssh[w0]; v.x += s.x; v.y += s.y; v.z += s.z; v.w += s.w; }
            if (w1 >= 0) { float4 s = ssh[w1]; v.x += s.x; v.y += s.y; v.z += s.z; v.w += s.w; }
            ushort4 u;
            u.x = f2bf(v.x); u.y = f2bf(v.y); u.z = f2bf(v.z); u.w = f2bf(v.w);
            *(ushort4*)(Gb + (size_t)(ibase + a) * KDIM + 4 * p) = u;
        }
    }
    grid.sync();

    // ---- P3: MFMA GEMM part[ks] += G_tile @ W^T_tile, fragments straight from L2
    {
        int w = (blockIdx.x << 3) + (tid >> 6);   // global wave id 0..2047
        int lane = tid & 63;
        int mt = w >> 5;          // 64 m-tiles of 16 rows
        int nt = (w >> 2) & 7;    // 8 n-tiles of 16 cols
        int ks = w & 3;           // 4 k-splits of 512
        int r16 = lane & 15, quad = lane >> 4;
        const ushort* Ga = Gb + (size_t)(mt * 16 + r16) * KDIM + ks * 512 + quad * 8;
        const ushort* Wa = Wb + (size_t)(nt * 16 + r16) * KDIM + ks * 512 + quad * 8;
        floatx4 acc = {0.f, 0.f, 0.f, 0.f};
#pragma unroll
        for (int kb = 0; kb < 16; ++kb) {
            short8 av = *(const short8*)(Ga + kb * 32);
            short8 bv = *(const short8*)(Wa + kb * 32);
            acc = __builtin_amdgcn_mfma_f32_16x16x32_bf16(av, bv, acc, 0, 0, 0);
        }
        // C/D layout (m89-verified): col = lane&15, row = quad*4 + reg
        float* pp = part + ((size_t)(ks * N_AGENTS) + mt * 16 + quad * 4) * HIDDEN + nt * 16 + r16;
#pragma unroll
        for (int r = 0; r < 4; ++r) pp[(size_t)r * HIDDEN] = acc[r];
    }
    grid.sync();

    // ---- P4: out = bias + sum of 4 split-K partials (deterministic fp32)
    {
        float s = bias[gt & (HIDDEN - 1)];
#pragma unroll
        for (int y = 0; y < NSPLIT; ++y)
            s += part[(size_t)y * (N_AGENTS * HIDDEN) + gt];
        out[gt] = s;
    }
}

extern "C" void kernel_launch(void* const* d_in, const int* in_sizes, int n_in,
                              void* d_out, int out_size, void* d_ws, size_t ws_size,
                              hipStream_t stream) {
    const float* hidden = (const float*)d_in[0];
    // d_in[1] = obs1 — unused by the reference
    const float* obs2   = (const float*)d_in[2];
    const float* W      = (const float*)d_in[3];
    const float* b      = (const float*)d_in[4];
    float* out = (float*)d_out;

    float*  Sh   = (float*) d_ws;                            // 16 KB
    ushort* Wb   = (ushort*)((char*)d_ws + 65536);           // 512 KB bf16 W
    ushort* Gb   = (ushort*)((char*)d_ws + (1u << 20));      // 4 MB bf16 G
    float*  part = (float*) ((char*)d_ws + (5u << 20));      // 2 MB split-K partials

    void* args[] = {&hidden, &obs2, &W, &b, &out, &Sh, &Wb, &Gb, &part};
    hipLaunchCooperativeKernel((const void*)k_fused, dim3(NBLK), dim3(NTHR),
                               args, 0, stream);
}

// Round 4
// 78.138 us; speedup vs baseline: 2.2024x; 2.2024x over previous
//
#include <hip/hip_runtime.h>
#include <math.h>

#define N_AGENTS 1024
#define HIDDEN   128
#define GRIDSZ   32
#define NCELLS   1024
#define KDIM     2048

typedef __attribute__((ext_vector_type(8))) short short8;   // 8 bf16 = 4 VGPRs
typedef __attribute__((ext_vector_type(4))) float floatx4;  // MFMA accumulator

static __device__ __forceinline__ ushort f2bf(float x) {   // RNE fp32->bf16
    union { float f; unsigned u; } v; v.f = x;
    return (ushort)((v.u + 0x7fffu + ((v.u >> 16) & 1u)) >> 16);
}

// K1: Wb = bf16(W); Sh table; out = bias (full overwrite so K3 can accumulate)
__global__ __launch_bounds__(256) void k_prep(const float* __restrict__ hidden,
                                              const float* __restrict__ W,
                                              const float* __restrict__ bias,
                                              float* __restrict__ Sh,
                                              ushort* __restrict__ Wb,
                                              float* __restrict__ out) {
    int gt = blockIdx.x * 256 + threadIdx.x;   // 0..131071
    {   // W: 262144 elems, 2 per thread
        float2 w2 = ((const float2*)W)[gt];
        ((unsigned*)Wb)[gt] = (unsigned)f2bf(w2.x) | ((unsigned)f2bf(w2.y) << 16);
    }
    out[gt] = bias[gt & (HIDDEN - 1)];
    if (gt < N_AGENTS * 4) {   // Sh[j][c] = sum over d with ((d>>3)&3)==c of hidden[j][d]
        int j = gt >> 2, c = gt & 3;
        const float* h = hidden + j * HIDDEN + c * 8;
        float s = 0.f;
#pragma unroll
        for (int u = 0; u < 4; ++u) {
            float4 a = *(const float4*)(h + u * 32);
            float4 b = *(const float4*)(h + u * 32 + 4);
            s += a.x + a.y + a.z + a.w + b.x + b.y + b.z + b.w;
        }
        Sh[gt] = s;
    }
}

// K2: 4 agents per block; one j-scan fills 4 winner grids (set semantics == max j),
// then pooled 2048-wide rows -> bf16 Gb.
__global__ __launch_bounds__(512) void k_grid(const float* __restrict__ obs2,
                                              const float4* __restrict__ Sh4,
                                              ushort* __restrict__ Gb) {
    __shared__ float2 spos[N_AGENTS];   // 8 KB
    __shared__ float4 ssh[N_AGENTS];    // 16 KB
    __shared__ int win[4][NCELLS];      // 16 KB
    const int tid = threadIdx.x;
    const float2* o2 = (const float2*)obs2;
    for (int j = tid; j < N_AGENTS; j += 512) {   // 2 iters
        spos[j] = o2[j];
        ssh[j] = Sh4[j];
    }
#pragma unroll
    for (int a = 0; a < 4; ++a)
        for (int c = tid; c < NCELLS; c += 512)
            win[a][c] = -1;
    __syncthreads();
    const int ibase = blockIdx.x * 4;
    float2 pi[4];
#pragma unroll
    for (int a = 0; a < 4; ++a) pi[a] = spos[ibase + a];
    for (int j = tid; j < N_AGENTS; j += 512) {   // 2 iters
        float2 pj = spos[j];
        if (isnan(pj.x)) continue;
#pragma unroll
        for (int a = 0; a < 4; ++a) {
            if (j == ibase + a) continue;
            // exact reference fp32 math: /0.125 == *8 (exact pow2), then +16
            float rx = (pj.x - pi[a].x) * 8.0f + 16.0f;   // NaN pi -> cmps false
            float ry = (pj.y - pi[a].y) * 8.0f + 16.0f;
            if (rx >= 0.f && rx < 32.f && ry >= 0.f && ry < 32.f)
                atomicMax(&win[a][(int)rx * GRIDSZ + (int)ry], j);
        }
    }
    __syncthreads();
    int p = tid;   // cell-pair 0..511
#pragma unroll
    for (int a = 0; a < 4; ++a) {
        int w0 = win[a][2 * p], w1 = win[a][2 * p + 1];
        float4 v = {0.f, 0.f, 0.f, 0.f};
        if (w0 >= 0) { float4 s = ssh[w0]; v.x += s.x; v.y += s.y; v.z += s.z; v.w += s.w; }
        if (w1 >= 0) { float4 s = ssh[w1]; v.x += s.x; v.y += s.y; v.z += s.z; v.w += s.w; }
        ushort4 u;
        u.x = f2bf(v.x); u.y = f2bf(v.y); u.z = f2bf(v.z); u.w = f2bf(v.w);
        *(ushort4*)(Gb + (size_t)(ibase + a) * KDIM + 4 * p) = u;
    }
}

// K3: per-wave 16x16 MFMA tile, fragments straight from L2, split-K=4,
// fp32 atomicAdd into bias-initialized out.
__global__ __launch_bounds__(256) void k_mfma(const ushort* __restrict__ Gb,
                                              const ushort* __restrict__ Wb,
                                              float* __restrict__ out) {
    int w = blockIdx.x * 4 + (threadIdx.x >> 6);   // wave 0..2047
    int lane = threadIdx.x & 63;
    int mt = w >> 5;          // 64 m-tiles of 16 rows
    int nt = (w >> 2) & 7;    // 8 n-tiles of 16 cols
    int ks = w & 3;           // 4 k-splits of 512
    int r16 = lane & 15, quad = lane >> 4;
    const ushort* Ga = Gb + (size_t)(mt * 16 + r16) * KDIM + ks * 512 + quad * 8;
    const ushort* Wa = Wb + (size_t)(nt * 16 + r16) * KDIM + ks * 512 + quad * 8;
    floatx4 acc = {0.f, 0.f, 0.f, 0.f};
#pragma unroll
    for (int kb = 0; kb < 16; ++kb) {
        short8 av = *(const short8*)(Ga + kb * 32);
        short8 bv = *(const short8*)(Wa + kb * 32);
        acc = __builtin_amdgcn_mfma_f32_16x16x32_bf16(av, bv, acc, 0, 0, 0);
    }
    // C/D layout (m89-verified): col = lane&15, row = quad*4 + reg
    float* o = out + (size_t)(mt * 16 + quad * 4) * HIDDEN + nt * 16 + r16;
#pragma unroll
    for (int r = 0; r < 4; ++r) atomicAdd(&o[(size_t)r * HIDDEN], acc[r]);
}

extern "C" void kernel_launch(void* const* d_in, const int* in_sizes, int n_in,
                              void* d_out, int out_size, void* d_ws, size_t ws_size,
                              hipStream_t stream) {
    const float* hidden = (const float*)d_in[0];
    // d_in[1] = obs1 — unused by the reference
    const float* obs2   = (const float*)d_in[2];
    const float* W      = (const float*)d_in[3];
    const float* b      = (const float*)d_in[4];
    float* out = (float*)d_out;

    float*  Sh = (float*) d_ws;                          // 16 KB
    ushort* Wb = (ushort*)((char*)d_ws + 65536);         // 512 KB bf16 W
    ushort* Gb = (ushort*)((char*)d_ws + (1u << 20));    // 4 MB bf16 G

    k_prep<<<512, 256, 0, stream>>>(hidden, W, b, Sh, Wb, out);
    k_grid<<<256, 512, 0, stream>>>(obs2, (const float4*)Sh, Gb);
    k_mfma<<<512, 256, 0, stream>>>(Gb, Wb, out);
}